// Round 1
// baseline (540.702 us; speedup 1.0000x reference)
//
#include <hip/hip_runtime.h>
#include <hip/hip_bf16.h>
#include <cstdint>
#include <cstddef>

// Problem dims (fixed)
#define BB 16
#define LL 2048
#define MM (BB * LL)   // 32768 rows
#define KK 1024        // inner dim
#define HH 1024        // hidden per gate

typedef __attribute__((ext_vector_type(8))) short bf16x8;
typedef __attribute__((ext_vector_type(4))) float f32x4;

// ---------- fp32 -> bf16 (RNE) ----------
__device__ __forceinline__ unsigned short f2bf(float f) {
    unsigned u = __builtin_bit_cast(unsigned, f);
    u += 0x7fffu + ((u >> 16) & 1u);
    return (unsigned short)(u >> 16);
}

__global__ void cvt_f32_to_bf16(const float* __restrict__ in,
                                unsigned short* __restrict__ out, int n8) {
    int i = blockIdx.x * blockDim.x + threadIdx.x;
    if (i >= n8) return;
    const float4* p = reinterpret_cast<const float4*>(in) + (size_t)i * 2;
    float4 v0 = p[0];
    float4 v1 = p[1];
    union { unsigned short us[8]; uint4 v; } o;
    o.us[0] = f2bf(v0.x); o.us[1] = f2bf(v0.y);
    o.us[2] = f2bf(v0.z); o.us[3] = f2bf(v0.w);
    o.us[4] = f2bf(v1.x); o.us[5] = f2bf(v1.y);
    o.us[6] = f2bf(v1.z); o.us[7] = f2bf(v1.w);
    reinterpret_cast<uint4*>(out)[i] = o.v;
}

// ---------- async global->LDS, 16B per lane ----------
__device__ __forceinline__ void gload16(const unsigned short* g, unsigned short* l) {
    __builtin_amdgcn_global_load_lds(
        (const __attribute__((address_space(1))) unsigned int*)g,
        (__attribute__((address_space(3))) unsigned int*)l,
        16, 0, 0);
}

// ---------- fused GEMM + GRU gating ----------
// A:[MM][KK] bf16 row-major, W:[3*HH][KK] bf16 row-major (K contiguous = B^T layout)
// g[m,h+g*HH] = sum_k A[m,k] * W[g*HH+h, k]
// r = sigmoid(g_r + bi_r + bh_r); z = sigmoid(g_z + bi_z + bh_z)
// n = tanh(g_n + bi_n + r*bh_n);  h = (1-z)*n
// MODE 0: write h as bf16 to out_bf[m*HH + h]
// MODE 1: write (h * mask[m]) as f32 to out_f[(l*BB + b)*HH + h], m = b*LL + l
template <int MODE>
__global__ __launch_bounds__(256, 2) void gru_layer(
    const unsigned short* __restrict__ A,
    const unsigned short* __restrict__ W,
    const float* __restrict__ b_ih,
    const float* __restrict__ b_hh,
    const int* __restrict__ mask,
    unsigned short* __restrict__ out_bf,
    float* __restrict__ out_f) {
    constexpr int BM = 128, BN = 64, BK = 32;
    __shared__ unsigned short As[BM * BK];       // [128][32] 8KB
    __shared__ unsigned short Bs[3 * BN * BK];   // [3][64][32] 12KB

    const int tid  = threadIdx.x;
    const int lane = tid & 63;
    const int wid  = tid >> 6;
    const int wr   = wid >> 1;  // 0..1  (wave row)
    const int wc   = wid & 1;   // 0..1  (wave col)

    const int m0 = blockIdx.x * BM;
    const int n0 = blockIdx.y * BN;

    // --- staging addresses: thread t covers row t/4, k-chunk (t%4)*8 ---
    const unsigned short* a_src  = A + (size_t)(m0 + (tid >> 2)) * KK + (tid & 3) * 8;
    const unsigned short* b_src0 = W + (size_t)(0 * HH + n0 + (tid >> 2)) * KK + (tid & 3) * 8;
    const unsigned short* b_src1 = W + (size_t)(1 * HH + n0 + (tid >> 2)) * KK + (tid & 3) * 8;
    const unsigned short* b_src2 = W + (size_t)(2 * HH + n0 + (tid >> 2)) * KK + (tid & 3) * 8;
    // wave-uniform LDS bases (lane writes base + lane*16)
    unsigned short* a_dst0 = &As[wid * 512];          // rows 0..63
    unsigned short* a_dst1 = &As[2048 + wid * 512];   // rows 64..127
    unsigned short* b_dst0 = &Bs[0 * 2048 + wid * 512];
    unsigned short* b_dst1 = &Bs[1 * 2048 + wid * 512];
    unsigned short* b_dst2 = &Bs[2 * 2048 + wid * 512];

    // --- MFMA fragment LDS offsets (lane l: row = base + (l&15), k0 = (l>>4)*8) ---
    int a_off[4], b_off[2];
#pragma unroll
    for (int mf = 0; mf < 4; ++mf)
        a_off[mf] = (wr * 64 + mf * 16 + (lane & 15)) * BK + (lane >> 4) * 8;
#pragma unroll
    for (int nf = 0; nf < 2; ++nf)
        b_off[nf] = (wc * 32 + nf * 16 + (lane & 15)) * BK + (lane >> 4) * 8;

    f32x4 accr[4][2] = {};
    f32x4 accz[4][2] = {};
    f32x4 accn[4][2] = {};

    for (int k0 = 0; k0 < KK; k0 += BK) {
        __syncthreads();  // previous iter's ds_reads done before overwrite
        gload16(a_src + k0, a_dst0);
        gload16(a_src + (size_t)64 * KK + k0, a_dst1);
        gload16(b_src0 + k0, b_dst0);
        gload16(b_src1 + k0, b_dst1);
        gload16(b_src2 + k0, b_dst2);
        __syncthreads();  // compiler drains vmcnt(0) before s_barrier

        bf16x8 af[4];
#pragma unroll
        for (int mf = 0; mf < 4; ++mf)
            af[mf] = *reinterpret_cast<const bf16x8*>(&As[a_off[mf]]);
#pragma unroll
        for (int nf = 0; nf < 2; ++nf) {
            bf16x8 br  = *reinterpret_cast<const bf16x8*>(&Bs[b_off[nf]]);
            bf16x8 bz  = *reinterpret_cast<const bf16x8*>(&Bs[2048 + b_off[nf]]);
            bf16x8 bnn = *reinterpret_cast<const bf16x8*>(&Bs[4096 + b_off[nf]]);
#pragma unroll
            for (int mf = 0; mf < 4; ++mf) {
                accr[mf][nf] = __builtin_amdgcn_mfma_f32_16x16x32_bf16(af[mf], br,  accr[mf][nf], 0, 0, 0);
                accz[mf][nf] = __builtin_amdgcn_mfma_f32_16x16x32_bf16(af[mf], bz,  accz[mf][nf], 0, 0, 0);
                accn[mf][nf] = __builtin_amdgcn_mfma_f32_16x16x32_bf16(af[mf], bnn, accn[mf][nf], 0, 0, 0);
            }
        }
    }

    // --- epilogue: gating (C/D layout: col = lane&15, row = (lane>>4)*4 + j) ---
#pragma unroll
    for (int nf = 0; nf < 2; ++nf) {
        const int col = n0 + wc * 32 + nf * 16 + (lane & 15);
        const float br_b = b_ih[col] + b_hh[col];
        const float bz_b = b_ih[HH + col] + b_hh[HH + col];
        const float bn_i = b_ih[2 * HH + col];
        const float bn_h = b_hh[2 * HH + col];
#pragma unroll
        for (int mf = 0; mf < 4; ++mf) {
#pragma unroll
            for (int j = 0; j < 4; ++j) {
                const int row = m0 + wr * 64 + mf * 16 + (lane >> 4) * 4 + j;
                const float r = 1.f / (1.f + __expf(-(accr[mf][nf][j] + br_b)));
                const float z = 1.f / (1.f + __expf(-(accz[mf][nf][j] + bz_b)));
                const float n = tanhf(accn[mf][nf][j] + bn_i + r * bn_h);
                float h = (1.f - z) * n;
                if (MODE == 0) {
                    out_bf[(size_t)row * HH + col] = f2bf(h);
                } else {
                    const int bb = row >> 11;    // row / LL
                    const int ll = row & 2047;   // row % LL
                    h *= (float)mask[row];       // mask[(b,l)] == mask[row]
                    out_f[((size_t)ll * BB + bb) * HH + col] = h;
                }
            }
        }
    }
}

extern "C" void kernel_launch(void* const* d_in, const int* in_sizes, int n_in,
                              void* d_out, int out_size, void* d_ws, size_t ws_size,
                              hipStream_t stream) {
    const float* x   = (const float*)d_in[0];
    const int*   msk = (const int*)d_in[1];
    const float* W0  = (const float*)d_in[2];
    const float* bi0 = (const float*)d_in[4];
    const float* bh0 = (const float*)d_in[5];
    const float* W1  = (const float*)d_in[6];
    const float* bi1 = (const float*)d_in[8];
    const float* bh1 = (const float*)d_in[9];
    float* out = (float*)d_out;

    char* ws = (char*)d_ws;
    unsigned short* xbf  = (unsigned short*)ws;                          // 67,108,864 B
    unsigned short* h1bf = (unsigned short*)(ws + 67108864);             // 67,108,864 B
    unsigned short* w0bf = (unsigned short*)(ws + 134217728);            //  6,291,456 B
    unsigned short* w1bf = (unsigned short*)(ws + 140509184);            //  6,291,456 B

    // fp32 -> bf16 conversions
    cvt_f32_to_bf16<<<16384, 256, 0, stream>>>(x, xbf, MM * KK / 8);
    cvt_f32_to_bf16<<<1536, 256, 0, stream>>>(W0, w0bf, 3 * HH * KK / 8);
    cvt_f32_to_bf16<<<1536, 256, 0, stream>>>(W1, w1bf, 3 * HH * KK / 8);

    dim3 grid(MM / 128, HH / 64);  // (256, 16)
    gru_layer<0><<<grid, 256, 0, stream>>>(xbf, w0bf, bi0, bh0, nullptr, h1bf, nullptr);
    gru_layer<1><<<grid, 256, 0, stream>>>(h1bf, w1bf, bi1, bh1, msk, nullptr, out);
}

// Round 2
// 374.500 us; speedup vs baseline: 1.4438x; 1.4438x over previous
//
#include <hip/hip_runtime.h>
#include <hip/hip_bf16.h>
#include <cstdint>
#include <cstddef>

// Problem dims (fixed)
#define BB 16
#define LL 2048
#define MM (BB * LL)   // 32768 rows
#define KK 1024        // inner dim
#define HH 1024        // hidden per gate

typedef __attribute__((ext_vector_type(8))) short bf16x8;
typedef __attribute__((ext_vector_type(4))) float f32x4;

// ---------- fp32 -> bf16 (RNE) ----------
__device__ __forceinline__ unsigned short f2bf(float f) {
    unsigned u = __builtin_bit_cast(unsigned, f);
    u += 0x7fffu + ((u >> 16) & 1u);
    return (unsigned short)(u >> 16);
}

__global__ void cvt_f32_to_bf16(const float* __restrict__ in,
                                unsigned short* __restrict__ out, int n8) {
    int i = blockIdx.x * blockDim.x + threadIdx.x;
    if (i >= n8) return;
    const float4* p = reinterpret_cast<const float4*>(in) + (size_t)i * 2;
    float4 v0 = p[0];
    float4 v1 = p[1];
    union { unsigned short us[8]; uint4 v; } o;
    o.us[0] = f2bf(v0.x); o.us[1] = f2bf(v0.y);
    o.us[2] = f2bf(v0.z); o.us[3] = f2bf(v0.w);
    o.us[4] = f2bf(v1.x); o.us[5] = f2bf(v1.y);
    o.us[6] = f2bf(v1.z); o.us[7] = f2bf(v1.w);
    reinterpret_cast<uint4*>(out)[i] = o.v;
}

// ---------- mask scan: rows[] = original indices of active rows, *Na = count ----------
__global__ __launch_bounds__(1024) void scan_mask(const int* __restrict__ mask,
                                                  int* __restrict__ rows,
                                                  int* __restrict__ Na) {
    __shared__ int psum[1024];
    const int t = threadIdx.x;
    const int base = t * 32;
    int m[32];
    int cnt = 0;
#pragma unroll
    for (int i = 0; i < 32; ++i) { m[i] = mask[base + i]; cnt += (m[i] != 0); }
    psum[t] = cnt;
    __syncthreads();
    // Hillis-Steele inclusive scan
    for (int off = 1; off < 1024; off <<= 1) {
        int v = (t >= off) ? psum[t - off] : 0;
        __syncthreads();
        psum[t] += v;
        __syncthreads();
    }
    int offset = psum[t] - cnt;  // exclusive prefix
#pragma unroll
    for (int i = 0; i < 32; ++i) {
        if (m[i]) rows[offset++] = base + i;
    }
    if (t == 1023) *Na = psum[1023];
}

// ---------- gather active rows of x, converting f32 -> bf16 ----------
// block j handles compact row j (256 threads x float4 = 1024 elems)
__global__ __launch_bounds__(256) void gather_cvt(const float* __restrict__ x,
                                                  const int* __restrict__ rows,
                                                  const int* __restrict__ Na,
                                                  unsigned short* __restrict__ xbf) {
    const int j = blockIdx.x;
    if (j >= *Na) return;
    const int r = rows[j];
    const float4 v = reinterpret_cast<const float4*>(x + (size_t)r * KK)[threadIdx.x];
    ushort4 o;
    o.x = f2bf(v.x); o.y = f2bf(v.y); o.z = f2bf(v.z); o.w = f2bf(v.w);
    reinterpret_cast<ushort4*>(xbf + (size_t)j * KK)[threadIdx.x] = o;
}

// ---------- write exact zeros to masked-out output rows ----------
__global__ __launch_bounds__(256) void zero_masked(const int* __restrict__ mask,
                                                   float* __restrict__ out) {
    const int m = blockIdx.x;
    if (mask[m] != 0) return;
    const int bb = m >> 11;   // b
    const int ll = m & 2047;  // l
    float4 z = {0.f, 0.f, 0.f, 0.f};
    reinterpret_cast<float4*>(out + ((size_t)ll * BB + bb) * HH)[threadIdx.x] = z;
}

// ---------- async global->LDS, 16B per lane ----------
__device__ __forceinline__ void gload16(const unsigned short* g, unsigned short* l) {
    __builtin_amdgcn_global_load_lds(
        (const __attribute__((address_space(1))) unsigned int*)g,
        (__attribute__((address_space(3))) unsigned int*)l,
        16, 0, 0);
}

// ---------- fused GEMM + GRU gating over COMPACTED rows ----------
// A:[Na][KK] bf16 row-major (compact), W:[3*HH][KK] bf16 row-major
// MODE 0: write h as bf16 to out_bf[j*HH + h] (compact)
// MODE 1: scatter h as f32 to out_f[(l*BB + b)*HH + h], (b,l) from rows[j]
template <int MODE>
__global__ __launch_bounds__(256, 2) void gru_layer(
    const unsigned short* __restrict__ A,
    const unsigned short* __restrict__ W,
    const float* __restrict__ b_ih,
    const float* __restrict__ b_hh,
    const int* __restrict__ rows,
    const int* __restrict__ Na_p,
    unsigned short* __restrict__ out_bf,
    float* __restrict__ out_f) {
    constexpr int BM = 128, BN = 64, BK = 32;
    __shared__ unsigned short As[BM * BK];       // [128][32] 8KB
    __shared__ unsigned short Bs[3 * BN * BK];   // [3][64][32] 12KB

    const int Na = *Na_p;
    const int m0 = blockIdx.x * BM;
    if (m0 >= Na) return;

    const int tid  = threadIdx.x;
    const int lane = tid & 63;
    const int wid  = tid >> 6;
    const int wr   = wid >> 1;  // 0..1  (wave row)
    const int wc   = wid & 1;   // 0..1  (wave col)
    const int n0 = blockIdx.y * BN;

    // --- staging addresses: thread t covers row t/4, k-chunk (t%4)*8 (rows clamped) ---
    int ar0 = m0 + (tid >> 2);        if (ar0 >= Na) ar0 = Na - 1;
    int ar1 = m0 + 64 + (tid >> 2);   if (ar1 >= Na) ar1 = Na - 1;
    const unsigned short* a_src0 = A + (size_t)ar0 * KK + (tid & 3) * 8;
    const unsigned short* a_src1 = A + (size_t)ar1 * KK + (tid & 3) * 8;
    const unsigned short* b_src0 = W + (size_t)(0 * HH + n0 + (tid >> 2)) * KK + (tid & 3) * 8;
    const unsigned short* b_src1 = W + (size_t)(1 * HH + n0 + (tid >> 2)) * KK + (tid & 3) * 8;
    const unsigned short* b_src2 = W + (size_t)(2 * HH + n0 + (tid >> 2)) * KK + (tid & 3) * 8;
    // wave-uniform LDS bases (lane writes base + lane*16)
    unsigned short* a_dst0 = &As[wid * 512];          // rows 0..63
    unsigned short* a_dst1 = &As[2048 + wid * 512];   // rows 64..127
    unsigned short* b_dst0 = &Bs[0 * 2048 + wid * 512];
    unsigned short* b_dst1 = &Bs[1 * 2048 + wid * 512];
    unsigned short* b_dst2 = &Bs[2 * 2048 + wid * 512];

    // --- MFMA fragment LDS offsets (lane l: row = base + (l&15), k0 = (l>>4)*8) ---
    int a_off[4], b_off[2];
#pragma unroll
    for (int mf = 0; mf < 4; ++mf)
        a_off[mf] = (wr * 64 + mf * 16 + (lane & 15)) * BK + (lane >> 4) * 8;
#pragma unroll
    for (int nf = 0; nf < 2; ++nf)
        b_off[nf] = (wc * 32 + nf * 16 + (lane & 15)) * BK + (lane >> 4) * 8;

    f32x4 accr[4][2] = {};
    f32x4 accz[4][2] = {};
    f32x4 accn[4][2] = {};

    for (int k0 = 0; k0 < KK; k0 += BK) {
        __syncthreads();  // previous iter's ds_reads done before overwrite
        gload16(a_src0 + k0, a_dst0);
        gload16(a_src1 + k0, a_dst1);
        gload16(b_src0 + k0, b_dst0);
        gload16(b_src1 + k0, b_dst1);
        gload16(b_src2 + k0, b_dst2);
        __syncthreads();  // drains vmcnt(0) before s_barrier

        bf16x8 af[4];
#pragma unroll
        for (int mf = 0; mf < 4; ++mf)
            af[mf] = *reinterpret_cast<const bf16x8*>(&As[a_off[mf]]);
#pragma unroll
        for (int nf = 0; nf < 2; ++nf) {
            bf16x8 br  = *reinterpret_cast<const bf16x8*>(&Bs[b_off[nf]]);
            bf16x8 bz  = *reinterpret_cast<const bf16x8*>(&Bs[2048 + b_off[nf]]);
            bf16x8 bnn = *reinterpret_cast<const bf16x8*>(&Bs[4096 + b_off[nf]]);
#pragma unroll
            for (int mf = 0; mf < 4; ++mf) {
                accr[mf][nf] = __builtin_amdgcn_mfma_f32_16x16x32_bf16(af[mf], br,  accr[mf][nf], 0, 0, 0);
                accz[mf][nf] = __builtin_amdgcn_mfma_f32_16x16x32_bf16(af[mf], bz,  accz[mf][nf], 0, 0, 0);
                accn[mf][nf] = __builtin_amdgcn_mfma_f32_16x16x32_bf16(af[mf], bnn, accn[mf][nf], 0, 0, 0);
            }
        }
    }

    // --- epilogue: gating (C/D layout: col = lane&15, row = (lane>>4)*4 + j) ---
#pragma unroll
    for (int nf = 0; nf < 2; ++nf) {
        const int col = n0 + wc * 32 + nf * 16 + (lane & 15);
        const float br_b = b_ih[col] + b_hh[col];
        const float bz_b = b_ih[HH + col] + b_hh[HH + col];
        const float bn_i = b_ih[2 * HH + col];
        const float bn_h = b_hh[2 * HH + col];
#pragma unroll
        for (int mf = 0; mf < 4; ++mf) {
#pragma unroll
            for (int j = 0; j < 4; ++j) {
                const int row = m0 + wr * 64 + mf * 16 + (lane >> 4) * 4 + j;
                if (row >= Na) continue;
                const float r = 1.f / (1.f + __expf(-(accr[mf][nf][j] + br_b)));
                const float z = 1.f / (1.f + __expf(-(accz[mf][nf][j] + bz_b)));
                const float n = tanhf(accn[mf][nf][j] + bn_i + r * bn_h);
                const float h = (1.f - z) * n;
                if (MODE == 0) {
                    out_bf[(size_t)row * HH + col] = f2bf(h);
                } else {
                    const int orig = rows[row];
                    const int bb = orig >> 11;    // b
                    const int ll = orig & 2047;   // l
                    out_f[((size_t)ll * BB + bb) * HH + col] = h;
                }
            }
        }
    }
}

extern "C" void kernel_launch(void* const* d_in, const int* in_sizes, int n_in,
                              void* d_out, int out_size, void* d_ws, size_t ws_size,
                              hipStream_t stream) {
    const float* x   = (const float*)d_in[0];
    const int*   msk = (const int*)d_in[1];
    const float* W0  = (const float*)d_in[2];
    const float* bi0 = (const float*)d_in[4];
    const float* bh0 = (const float*)d_in[5];
    const float* W1  = (const float*)d_in[6];
    const float* bi1 = (const float*)d_in[8];
    const float* bh1 = (const float*)d_in[9];
    float* out = (float*)d_out;

    char* ws = (char*)d_ws;
    unsigned short* xbf  = (unsigned short*)ws;                  // 67,108,864 B (worst case)
    unsigned short* h1bf = (unsigned short*)(ws + 67108864);     // 67,108,864 B (worst case)
    unsigned short* w0bf = (unsigned short*)(ws + 134217728);    //  6,291,456 B
    unsigned short* w1bf = (unsigned short*)(ws + 140509184);    //  6,291,456 B
    int* rows = (int*)(ws + 146800640);                          //    131,072 B
    int* Na   = (int*)(ws + 146931712);                          //          4 B

    // mask scan -> compact row list
    scan_mask<<<1, 1024, 0, stream>>>(msk, rows, Na);

    // weight conversions (independent of scan)
    cvt_f32_to_bf16<<<1536, 256, 0, stream>>>(W0, w0bf, 3 * HH * KK / 8);
    cvt_f32_to_bf16<<<1536, 256, 0, stream>>>(W1, w1bf, 3 * HH * KK / 8);

    // exact zeros for masked-out output rows (d_out is not zeroed by harness)
    zero_masked<<<MM, 256, 0, stream>>>(msk, out);

    // gather + convert active rows of x
    gather_cvt<<<MM, 256, 0, stream>>>(x, rows, Na, xbf);

    dim3 grid(MM / 128, HH / 64);  // worst-case grid; blocks past Na early-exit
    gru_layer<0><<<grid, 256, 0, stream>>>(xbf, w0bf, bi0, bh0, rows, Na, h1bf, nullptr);
    gru_layer<1><<<grid, 256, 0, stream>>>(h1bf, w1bf, bi1, bh1, rows, Na, nullptr, out);
}